// Round 4
// 812.902 us; speedup vs baseline: 1.0608x; 1.0608x over previous
//
#include <hip/hip_runtime.h>
#include <hip/hip_bf16.h>

typedef __bf16 bf16x8 __attribute__((ext_vector_type(8)));
typedef __bf16 bf16x4 __attribute__((ext_vector_type(4)));
typedef float  f32x4  __attribute__((ext_vector_type(4)));

#define MFMA16(a, b, c) __builtin_amdgcn_mfma_f32_16x16x32_bf16((a), (b), (c), 0, 0, 0)

// async global->LDS copy, 16B per lane; LDS dest = wave-uniform base + lane*16
__device__ __forceinline__ void async_copy16(const void* g, void* l) {
    __builtin_amdgcn_global_load_lds(
        (const __attribute__((address_space(1))) void*)g,
        (__attribute__((address_space(3))) void*)l, 16, 0, 0);
}

// ---------------------------------------------------------------------------
__global__ void zero_stats_kernel(float* s) { s[threadIdx.x] = 0.0f; }

// ---------------------------------------------------------------------------
// Fused: GN1 stats (per-group sum/sumsq over f32 x) + cast x -> bf16 copy xb.
__global__ __launch_bounds__(256) void caststats_kernel(
    const float4* __restrict__ x, bf16x4* __restrict__ xb,
    float* __restrict__ stats, int nvec)
{
    int nth = gridDim.x * blockDim.x;
    int gt = blockIdx.x * blockDim.x + threadIdx.x;
    float s = 0.f, ss = 0.f;
    for (int f = gt; f < nvec; f += nth) {
        float4 v = x[f];
        s  += v.x + v.y + v.z + v.w;
        ss += v.x * v.x + v.y * v.y + v.z * v.z + v.w * v.w;
        bf16x4 b;
        b[0] = (__bf16)v.x; b[1] = (__bf16)v.y;
        b[2] = (__bf16)v.z; b[3] = (__bf16)v.w;
        xb[f] = b;
    }
    __shared__ float ls[16];
    if (threadIdx.x < 16) ls[threadIdx.x] = 0.f;
    __syncthreads();
    int g = gt & 7;
    atomicAdd(&ls[2 * g], s);
    atomicAdd(&ls[2 * g + 1], ss);
    __syncthreads();
    if (threadIdx.x < 16) atomicAdd(&stats[threadIdx.x], ls[threadIdx.x]);
}

// ---------------------------------------------------------------------------
// Fold GN1 affine into W1 (bf16 B-frag pack), pack Wskip, conv1 bias, feat.
// B-frag (mfma_f32_16x16x32_bf16): lane holds B[k=(lane>>4)*8+j][n=lane&15].
// bp1 index: [k][ct][lane][j] (27*4*64*8)
__global__ __launch_bounds__(256) void fold1_kernel(
    const float* __restrict__ W1, const float* __restrict__ gamma1,
    const float* __restrict__ beta1, const float* __restrict__ Wskip,
    const float* __restrict__ stats1,
    __bf16* __restrict__ bp1, __bf16* __restrict__ bps,
    float* __restrict__ bias1,
    const int* __restrict__ feat, int* __restrict__ feat_out, float inv_n)
{
    int b = blockIdx.x, t = threadIdx.x;
    if (b < 216) {
        int e = b * 256 + t;
        int j = e & 7, lane = (e >> 3) & 63, ct = (e >> 9) & 3, k = e >> 11;
        int ci = ((lane >> 4) << 3) + j;
        int co = (ct << 4) + (lane & 15);
        int g = ci >> 2;
        float mean = stats1[2 * g] * inv_n;
        float var  = stats1[2 * g + 1] * inv_n - mean * mean;
        float r = rsqrtf(var + 1e-5f);
        float a = gamma1[ci] * r;
        bp1[e] = (__bf16)(a * W1[k * 2048 + ci * 64 + co]);
    } else if (b == 216) {
        if (t < 64) {
            float sum = 0.0f;
            for (int ci = 0; ci < 32; ++ci) {
                int g = ci >> 2;
                float mean = stats1[2 * g] * inv_n;
                float var  = stats1[2 * g + 1] * inv_n - mean * mean;
                float r = rsqrtf(var + 1e-5f);
                float a = gamma1[ci] * r;
                float bb = beta1[ci] - mean * a;
                float ws = 0.0f;
                for (int k = 0; k < 27; ++k) ws += W1[k * 2048 + ci * 64 + t];
                sum += bb * ws;
            }
            bias1[t] = sum;
        } else if (t == 64) {
            feat_out[0] = feat[0];
        }
    } else {
        int e = (b - 217) * 256 + t;
        int j = e & 7, lane = (e >> 3) & 63, ct = e >> 9;
        int ci = ((lane >> 4) << 3) + j;
        int co = (ct << 4) + (lane & 15);
        bps[e] = (__bf16)Wskip[ci * 64 + co];
    }
}

// ---------------------------------------------------------------------------
// Fold GN2 into W2.  bp2 index: [k][hf][ct][lane][j]  (27*2*4*64*8)
__global__ __launch_bounds__(256) void fold2_kernel(
    const float* __restrict__ W2, const float* __restrict__ gamma2,
    const float* __restrict__ beta2, const float* __restrict__ stats2,
    __bf16* __restrict__ bp2, float* __restrict__ bias2, float inv_n)
{
    int b = blockIdx.x, t = threadIdx.x;
    if (b < 432) {
        int e = b * 256 + t;
        int j = e & 7, lane = (e >> 3) & 63, ct = (e >> 9) & 3, hf = (e >> 11) & 1, k = e >> 12;
        int ci = (hf << 5) + ((lane >> 4) << 3) + j;
        int co = (ct << 4) + (lane & 15);
        int g = ci >> 3;
        float mean = stats2[2 * g] * inv_n;
        float var  = stats2[2 * g + 1] * inv_n - mean * mean;
        float r = rsqrtf(var + 1e-5f);
        float a = gamma2[ci] * r;
        bp2[e] = (__bf16)(a * W2[k * 4096 + ci * 64 + co]);
    } else if (t < 64) {
        float sum = 0.0f;
        for (int ci = 0; ci < 64; ++ci) {
            int g = ci >> 3;
            float mean = stats2[2 * g] * inv_n;
            float var  = stats2[2 * g + 1] * inv_n - mean * mean;
            float r = rsqrtf(var + 1e-5f);
            float a = gamma2[ci] * r;
            float bb = beta2[ci] - mean * a;
            float ws = 0.0f;
            for (int k = 0; k < 27; ++k) ws += W2[k * 4096 + ci * 64 + t];
            sum += bb * ws;
        }
        bias2[t] = sum;
    }
}

// ---------------------------------------------------------------------------
// conv1: h[n,:64] = silu( sum_k xb[idx[n,k],:32] @ W1'[k] + bias1 )  (h bf16)
// + GN2 stats. 2 tiles per wave. B staged in LDS (3-tap chunks) so the vmcnt
// queue holds ONLY gathers -> depth-3 gather prefetch actually covers latency.
__global__ __launch_bounds__(256, 4) void conv1_kernel(
    const __bf16* __restrict__ xb, const int* __restrict__ nbr,
    const __bf16* __restrict__ bp1, const float* __restrict__ bias1,
    __bf16* __restrict__ h, float* __restrict__ stats2, int nTiles)
{
    __shared__ int sidx[4][864];
    __shared__ __align__(16) __bf16 Bs[3 * 2048];   // 3 taps x 4 KB = 12 KB
    __shared__ float ls[16];
    const int wav = threadIdx.x >> 6, lane = threadIdx.x & 63;
    const int unit = blockIdx.x * 4 + wav;
    const int t0 = unit * 2;
    const bool act0 = t0 < nTiles, act1 = t0 + 1 < nTiles;
    if (threadIdx.x < 16) ls[threadIdx.x] = 0.f;
    const int lm = lane & 15, q = lane >> 4;

    // stage neighbor indices (per-wave private; inactive waves clamp to tile 0)
    {
        const int tc = act0 ? t0 : 0;
        const int* gi = nbr + (size_t)tc * 432;
        const int cnt = (act0 && act1) ? 864 : 432;
        for (int i = lane; i < 864; i += 64) sidx[wav][i] = (i < cnt) ? gi[i] : 0;
    }
    const int* s0p = &sidx[wav][lm * 27];
    const int* s1p = &sidx[wav][432 + lm * 27];

    // stage B chunk 0 (taps 0..2): 12 wave-calls of 1 KB
#pragma unroll
    for (int i = 0; i < 3; ++i) {
        int part = wav * 3 + i;                      // 0..11
        async_copy16(bp1 + (size_t)part * 512 + lane * 8, &Bs[part * 512]);
    }

    f32x4 c[8] = {};
    bf16x8 P0[3], P1[3];                             // depth-3 gather pipeline
#pragma unroll
    for (int k = 0; k < 3; ++k) {
        P0[k] = *(const bf16x8*)(xb + (size_t)s0p[k] * 32 + q * 8);
        P1[k] = *(const bf16x8*)(xb + (size_t)s1p[k] * 32 + q * 8);
    }
    __syncthreads();                                 // Bs chunk 0 visible

    const bf16x8* Bv = (const bf16x8*)Bs;
#pragma unroll
    for (int k = 0; k < 27; ++k) {
        const int sl = k % 3;
        bf16x8 n0, n1;
        if (k + 3 < 27) {
            n0 = *(const bf16x8*)(xb + (size_t)s0p[k + 3] * 32 + q * 8);
            n1 = *(const bf16x8*)(xb + (size_t)s1p[k + 3] * 32 + q * 8);
        }
        const int bb = sl * 256 + lane;
        bf16x8 b0 = Bv[bb], b1 = Bv[bb + 64], b2 = Bv[bb + 128], b3 = Bv[bb + 192];
        bf16x8 a0 = P0[sl], a1 = P1[sl];
        c[0] = MFMA16(a0, b0, c[0]);
        c[1] = MFMA16(a0, b1, c[1]);
        c[2] = MFMA16(a0, b2, c[2]);
        c[3] = MFMA16(a0, b3, c[3]);
        c[4] = MFMA16(a1, b0, c[4]);
        c[5] = MFMA16(a1, b1, c[5]);
        c[6] = MFMA16(a1, b2, c[6]);
        c[7] = MFMA16(a1, b3, c[7]);
        if (k + 3 < 27) { P0[sl] = n0; P1[sl] = n1; }
        if ((k % 3) == 2 && k < 26) {
            __syncthreads();                         // all waves done with chunk
            const __bf16* gsrc = bp1 + (size_t)(k / 3 + 1) * 3 * 2048;
#pragma unroll
            for (int i = 0; i < 3; ++i) {
                int part = wav * 3 + i;
                async_copy16(gsrc + (size_t)part * 512 + lane * 8, &Bs[part * 512]);
            }
            __syncthreads();                         // next chunk staged
        }
    }

    if (act0) {
        // C/D layout: col = lane&15 (cout), row = q*4 + r (voxel)
#define EPI1(CI, CT, V0) { \
        float bsv = bias1[(CT) * 16 + lm]; \
        float ps = 0.f, pss = 0.f; \
        _Pragma("unroll") \
        for (int r = 0; r < 4; ++r) { \
            float val = c[CI][r] + bsv; \
            val = val / (1.0f + __expf(-val)); \
            h[(size_t)((V0) + q * 4 + r) * 64 + (CT) * 16 + lm] = (__bf16)val; \
            ps += val; pss += val * val; } \
        int g2 = (CT) * 2 + (lm >> 3); \
        atomicAdd(&ls[2 * g2], ps); atomicAdd(&ls[2 * g2 + 1], pss); }
        const int v0 = t0 * 16;
        EPI1(0, 0, v0) EPI1(1, 1, v0) EPI1(2, 2, v0) EPI1(3, 3, v0)
        if (act1) {
            const int v1 = v0 + 16;
            EPI1(4, 0, v1) EPI1(5, 1, v1) EPI1(6, 2, v1) EPI1(7, 3, v1)
        }
#undef EPI1
    }
    __syncthreads();
    if (threadIdx.x < 16) atomicAdd(&stats2[threadIdx.x], ls[threadIdx.x]);
}

// ---------------------------------------------------------------------------
// conv2 + skip. 2 tiles per wave. B staged in LDS (3-tap chunks, 24 KB),
// depth-2 gather prefetch on a pure-gather vmcnt queue.
__global__ __launch_bounds__(256, 4) void conv2_kernel(
    const __bf16* __restrict__ h, const __bf16* __restrict__ xb,
    const int* __restrict__ nbr,
    const __bf16* __restrict__ bp2, const __bf16* __restrict__ bps,
    const float* __restrict__ bias2, const float* __restrict__ bskip,
    float* __restrict__ out, int nTiles)
{
    __shared__ int sidx[4][864];
    __shared__ __align__(16) __bf16 Bs[3 * 4096];   // 3 taps x 8 KB = 24 KB
    const int wav = threadIdx.x >> 6, lane = threadIdx.x & 63;
    const int unit = blockIdx.x * 4 + wav;
    const int t0 = unit * 2;
    const bool act0 = t0 < nTiles, act1 = t0 + 1 < nTiles;
    const int lm = lane & 15, q = lane >> 4;

    {
        const int tc = act0 ? t0 : 0;
        const int* gi = nbr + (size_t)tc * 432;
        const int cnt = (act0 && act1) ? 864 : 432;
        for (int i = lane; i < 864; i += 64) sidx[wav][i] = (i < cnt) ? gi[i] : 0;
    }
    const int* s0p = &sidx[wav][lm * 27];
    const int* s1p = &sidx[wav][432 + lm * 27];

    // stage B chunk 0 (taps 0..2): 24 wave-calls of 1 KB
#pragma unroll
    for (int i = 0; i < 6; ++i) {
        int part = wav * 6 + i;                      // 0..23
        async_copy16(bp2 + (size_t)part * 512 + lane * 8, &Bs[part * 512]);
    }

    f32x4 c[8] = {};
    bf16x8 P0l[2], P0h[2], P1l[2], P1h[2];           // depth-2 gather pipeline
#pragma unroll
    for (int k = 0; k < 2; ++k) {
        const __bf16* r0 = h + (size_t)s0p[k] * 64;
        const __bf16* r1 = h + (size_t)s1p[k] * 64;
        P0l[k] = *(const bf16x8*)(r0 + q * 8);
        P0h[k] = *(const bf16x8*)(r0 + 32 + q * 8);
        P1l[k] = *(const bf16x8*)(r1 + q * 8);
        P1h[k] = *(const bf16x8*)(r1 + 32 + q * 8);
    }
    __syncthreads();                                 // Bs chunk 0 visible

    const bf16x8* Bv = (const bf16x8*)Bs;
#pragma unroll
    for (int k = 0; k < 27; ++k) {
        const int sl = k & 1;
        bf16x8 n0l, n0h, n1l, n1h;
        if (k + 2 < 27) {
            const __bf16* p0 = h + (size_t)s0p[k + 2] * 64;
            const __bf16* p1 = h + (size_t)s1p[k + 2] * 64;
            n0l = *(const bf16x8*)(p0 + q * 8);
            n0h = *(const bf16x8*)(p0 + 32 + q * 8);
            n1l = *(const bf16x8*)(p1 + q * 8);
            n1h = *(const bf16x8*)(p1 + 32 + q * 8);
        }
        const int bb = (k % 3) * 512 + lane;
        bf16x8 b0 = Bv[bb],       b1 = Bv[bb + 64];
        bf16x8 b2 = Bv[bb + 128], b3 = Bv[bb + 192];
        bf16x8 a0l = P0l[sl], a0h = P0h[sl], a1l = P1l[sl], a1h = P1h[sl];
        c[0] = MFMA16(a0l, b0, c[0]);
        c[1] = MFMA16(a0l, b1, c[1]);
        c[2] = MFMA16(a0l, b2, c[2]);
        c[3] = MFMA16(a0l, b3, c[3]);
        c[4] = MFMA16(a1l, b0, c[4]);
        c[5] = MFMA16(a1l, b1, c[5]);
        c[6] = MFMA16(a1l, b2, c[6]);
        c[7] = MFMA16(a1l, b3, c[7]);
        bf16x8 b4 = Bv[bb + 256], b5 = Bv[bb + 320];
        bf16x8 b6 = Bv[bb + 384], b7 = Bv[bb + 448];
        c[0] = MFMA16(a0h, b4, c[0]);
        c[1] = MFMA16(a0h, b5, c[1]);
        c[2] = MFMA16(a0h, b6, c[2]);
        c[3] = MFMA16(a0h, b7, c[3]);
        c[4] = MFMA16(a1h, b4, c[4]);
        c[5] = MFMA16(a1h, b5, c[5]);
        c[6] = MFMA16(a1h, b6, c[6]);
        c[7] = MFMA16(a1h, b7, c[7]);
        if (k + 2 < 27) { P0l[sl] = n0l; P0h[sl] = n0h; P1l[sl] = n1l; P1h[sl] = n1h; }
        if ((k % 3) == 2 && k < 26) {
            __syncthreads();                         // all waves done with chunk
            const __bf16* gsrc = bp2 + (size_t)(k / 3 + 1) * 3 * 4096;
#pragma unroll
            for (int i = 0; i < 6; ++i) {
                int part = wav * 6 + i;
                async_copy16(gsrc + (size_t)part * 512 + lane * 8, &Bs[part * 512]);
            }
            __syncthreads();                         // next chunk staged
        }
    }

    if (!act0) return;
    // skip 1x1 conv after the K-loop (short accumulator live range)
    f32x4 s[8] = {};
    {
        const bf16x8* bsp = (const bf16x8*)bps;
        bf16x8 ax0 = *(const bf16x8*)(xb + ((size_t)t0 * 16 + lm) * 32 + q * 8);
        bf16x8 w0 = bsp[lane], w1 = bsp[64 + lane], w2 = bsp[128 + lane], w3 = bsp[192 + lane];
        s[0] = MFMA16(ax0, w0, s[0]);
        s[1] = MFMA16(ax0, w1, s[1]);
        s[2] = MFMA16(ax0, w2, s[2]);
        s[3] = MFMA16(ax0, w3, s[3]);
        if (act1) {
            bf16x8 ax1 = *(const bf16x8*)(xb + ((size_t)t0 * 16 + 16 + lm) * 32 + q * 8);
            s[4] = MFMA16(ax1, w0, s[4]);
            s[5] = MFMA16(ax1, w1, s[5]);
            s[6] = MFMA16(ax1, w2, s[6]);
            s[7] = MFMA16(ax1, w3, s[7]);
        }
    }
#define EPI2(CI, CT, V0) { \
        int co = (CT) * 16 + lm; \
        float b2v = bias2[co]; \
        float bsk = bskip[co]; \
        _Pragma("unroll") \
        for (int r = 0; r < 4; ++r) { \
            float val = c[CI][r] + b2v; \
            val = val / (1.0f + __expf(-val)); \
            val += s[CI][r] + bsk; \
            out[(size_t)((V0) + q * 4 + r) * 64 + co] = val; } }
    const int v0 = t0 * 16;
    EPI2(0, 0, v0) EPI2(1, 1, v0) EPI2(2, 2, v0) EPI2(3, 3, v0)
    if (act1) {
        const int v1 = v0 + 16;
        EPI2(4, 0, v1) EPI2(5, 1, v1) EPI2(6, 2, v1) EPI2(7, 3, v1)
    }
#undef EPI2
}

// ---------------------------------------------------------------------------
extern "C" void kernel_launch(void* const* d_in, const int* in_sizes, int n_in,
                              void* d_out, int out_size, void* d_ws, size_t ws_size,
                              hipStream_t stream)
{
    (void)n_in; (void)out_size; (void)ws_size;
    const float* x      = (const float*)d_in[0];
    const int*   nbr    = (const int*)d_in[1];
    const float* gamma1 = (const float*)d_in[2];
    const float* beta1  = (const float*)d_in[3];
    const float* W1     = (const float*)d_in[4];
    const float* gamma2 = (const float*)d_in[5];
    const float* beta2  = (const float*)d_in[6];
    const float* W2     = (const float*)d_in[7];
    const float* Wskip  = (const float*)d_in[8];
    const float* bskip  = (const float*)d_in[9];
    const int*   feat   = (const int*)d_in[10];
    const int N = in_sizes[0] / 32;

    char* ws = (char*)d_ws;
    float* stats1 = (float*)ws;                 // 16 floats
    float* stats2 = stats1 + 16;                // 16 floats
    float* bias1  = stats1 + 32;                // 64 floats
    float* bias2  = stats1 + 96;                // 64 floats
    __bf16* bp1 = (__bf16*)(ws + (1 << 10));    // 55296 elems
    __bf16* bps = (__bf16*)(ws + (1 << 17));    // 2048 elems
    __bf16* bp2 = (__bf16*)(ws + 144 * 1024);   // 110592 elems
    __bf16* xb  = (__bf16*)(ws + (1 << 20));    // N*32 bf16 = 32 MB
    __bf16* h   = (__bf16*)(ws + (size_t)34 * (1 << 20)); // N*64 bf16 = 64 MB
    float* outb = (float*)d_out;

    const int nTiles = (N + 15) / 16;           // 31250
    const int units = (nTiles + 1) / 2;         // 15625
    const int convBlocks = (units + 3) / 4;     // 3907

    hipLaunchKernelGGL(zero_stats_kernel, dim3(1), dim3(32), 0, stream, stats1);
    hipLaunchKernelGGL(caststats_kernel, dim3(2048), dim3(256), 0, stream,
                       (const float4*)x, (bf16x4*)xb, stats1, N * 8);
    hipLaunchKernelGGL(fold1_kernel, dim3(225), dim3(256), 0, stream,
                       W1, gamma1, beta1, Wskip, stats1, bp1, bps, bias1,
                       feat, (int*)(outb + (size_t)N * 64),
                       1.0f / (4.0f * (float)N));
    hipLaunchKernelGGL(conv1_kernel, dim3(convBlocks), dim3(256), 0, stream,
                       xb, nbr, bp1, bias1, h, stats2, nTiles);
    hipLaunchKernelGGL(fold2_kernel, dim3(433), dim3(256), 0, stream,
                       W2, gamma2, beta2, stats2, bp2, bias2,
                       1.0f / (8.0f * (float)N));
    hipLaunchKernelGGL(conv2_kernel, dim3(convBlocks), dim3(256), 0, stream,
                       h, xb, nbr, bp2, bps, bias2, bskip, outb, nTiles);
}